// Round 2
// baseline (121.149 us; speedup 1.0000x reference)
//
#include <hip/hip_runtime.h>

// Closed form of the reference (exact, since SIG = 1/sqrt(2pi) makes log_sqrt_pi = 0):
//   out = D + 0.5 * sum_{k=0}^{D-1} [ e^{-pi*(y[k+1]-y[k])^2} + e^{-pi*(d[k+1]-d[k])^2}
//                                   - e^{-pi*(d[k+1]-y[k+1])^2} - e^{-pi*(d[k+1]-y[k])^2}
//                                   - e^{-pi*(d[k]-y[k+1])^2}   - e^{-pi*(d[k]-y[k])^2} ]
// with D = N-2.  Single pass over d,y; scalar output.

#define PI_F 3.14159265358979323846f

__device__ __forceinline__ float six_terms(float d0, float d1, float y0, float y1) {
    float dy = y1 - y0;
    float dd = d1 - d0;
    float c00 = d1 - y1;
    float c01 = d1 - y0;
    float c10 = d0 - y1;
    float c11 = d0 - y0;
    return __expf(-PI_F * dy * dy) + __expf(-PI_F * dd * dd)
         - __expf(-PI_F * c00 * c00) - __expf(-PI_F * c01 * c01)
         - __expf(-PI_F * c10 * c10) - __expf(-PI_F * c11 * c11);
}

// One thread handles 4 consecutive k (float4 load + 1 scalar neighbor per array).
__global__ __launch_bounds__(256) void casamento_kernel(
    const float* __restrict__ d, const float* __restrict__ y,
    float* __restrict__ out, int D)
{
    int gid = blockIdx.x * blockDim.x + threadIdx.x;
    int D4 = D >> 2;            // number of 4-wide units
    float acc = 0.0f;

    if (gid < D4) {
        int base = gid << 2;
        float4 dv = *(const float4*)(d + base);
        float4 yv = *(const float4*)(y + base);
        float d4 = d[base + 4];
        float y4 = y[base + 4];

        acc += six_terms(dv.x, dv.y, yv.x, yv.y);
        acc += six_terms(dv.y, dv.z, yv.y, yv.z);
        acc += six_terms(dv.z, dv.w, yv.z, yv.w);
        acc += six_terms(dv.w, d4,   yv.w, y4);
    }

    // tail (D not divisible by 4): one thread mops up (<=3 elements)
    if (gid == 0) {
        for (int k = (D4 << 2); k < D; ++k)
            acc += six_terms(d[k], d[k + 1], y[k], y[k + 1]);
    }

    acc *= 0.5f;

    // wave-64 butterfly reduce
    for (int off = 32; off > 0; off >>= 1)
        acc += __shfl_down(acc, off, 64);

    __shared__ float warp_sums[4];  // 256 threads / 64 lanes
    int lane = threadIdx.x & 63;
    int wid  = threadIdx.x >> 6;
    if (lane == 0) warp_sums[wid] = acc;
    __syncthreads();

    if (threadIdx.x == 0) {
        float s = warp_sums[0] + warp_sums[1] + warp_sums[2] + warp_sums[3];
        if (blockIdx.x == 0) s += (float)D;  // constant term
        atomicAdd(out, s);
    }
}

extern "C" void kernel_launch(void* const* d_in, const int* in_sizes, int n_in,
                              void* d_out, int out_size, void* d_ws, size_t ws_size,
                              hipStream_t stream) {
    const float* d = (const float*)d_in[0];
    const float* y = (const float*)d_in[1];
    float* out = (float*)d_out;

    int N = in_sizes[0];
    int D = N - 2;
    int D4 = D >> 2;

    // d_out is poisoned 0xAA before every timed launch — zero the accumulator (4 B, capture-safe).
    hipMemsetAsync(out, 0, sizeof(float), stream);

    const int block = 256;
    int grid = (D4 + block - 1) / block;   // exact cover, no grid-stride loop
    if (grid < 1) grid = 1;
    casamento_kernel<<<grid, block, 0, stream>>>(d, y, out, D);
}

// Round 3
// 75.516 us; speedup vs baseline: 1.6043x; 1.6043x over previous
//
#include <hip/hip_runtime.h>

// Closed form of the reference (exact, since SIG = 1/sqrt(2pi) makes log_sqrt_pi = 0):
//   out = D + 0.5 * sum_{k=0}^{D-1} [ e^{-pi*(y[k+1]-y[k])^2} + e^{-pi*(d[k+1]-d[k])^2}
//                                   - e^{-pi*(d[k+1]-y[k+1])^2} - e^{-pi*(d[k+1]-y[k])^2}
//                                   - e^{-pi*(d[k]-y[k+1])^2}   - e^{-pi*(d[k]-y[k])^2} ]
// with D = N-2.
//
// R2 lesson: 3907 same-address atomicAdds serialized at the coherence point
// (~54 us kernel with all pipes idle). This version: per-block partials to
// distinct d_ws slots (no atomics), then a 1-block reduce kernel.

#define PI_F 3.14159265358979323846f
#define NBLOCKS 1024
#define FINAL_THREADS 1024

__device__ __forceinline__ float six_terms(float d0, float d1, float y0, float y1) {
    float dy = y1 - y0;
    float dd = d1 - d0;
    float c00 = d1 - y1;
    float c01 = d1 - y0;
    float c10 = d0 - y1;
    float c11 = d0 - y0;
    return __expf(-PI_F * dy * dy) + __expf(-PI_F * dd * dd)
         - __expf(-PI_F * c00 * c00) - __expf(-PI_F * c01 * c01)
         - __expf(-PI_F * c10 * c10) - __expf(-PI_F * c11 * c11);
}

// Stage 1: grid-stride over 4-wide units; per-block partial sum to ws[blockIdx].
__global__ __launch_bounds__(256) void casamento_partial(
    const float* __restrict__ d, const float* __restrict__ y,
    float* __restrict__ ws, int D)
{
    int tid = blockIdx.x * blockDim.x + threadIdx.x;
    int stride = gridDim.x * blockDim.x;
    int D4 = D >> 2;

    float acc = 0.0f;
    for (int u = tid; u < D4; u += stride) {
        int base = u << 2;
        float4 dv = *(const float4*)(d + base);
        float4 yv = *(const float4*)(y + base);
        float d4 = d[base + 4];
        float y4 = y[base + 4];

        acc += six_terms(dv.x, dv.y, yv.x, yv.y);
        acc += six_terms(dv.y, dv.z, yv.y, yv.z);
        acc += six_terms(dv.z, dv.w, yv.z, yv.w);
        acc += six_terms(dv.w, d4,   yv.w, y4);
    }

    // tail (D % 4 != 0): thread 0 of block 0 mops up (<=3 elements)
    if (tid == 0) {
        for (int k = (D4 << 2); k < D; ++k)
            acc += six_terms(d[k], d[k + 1], y[k], y[k + 1]);
    }

    acc *= 0.5f;

    // wave-64 butterfly reduce
    for (int off = 32; off > 0; off >>= 1)
        acc += __shfl_down(acc, off, 64);

    __shared__ float warp_sums[4];
    int lane = threadIdx.x & 63;
    int wid  = threadIdx.x >> 6;
    if (lane == 0) warp_sums[wid] = acc;
    __syncthreads();

    if (threadIdx.x == 0)
        ws[blockIdx.x] = warp_sums[0] + warp_sums[1] + warp_sums[2] + warp_sums[3];
}

// Stage 2: one block reduces NBLOCKS partials, adds constant D, writes out[0].
__global__ __launch_bounds__(FINAL_THREADS) void casamento_final(
    const float* __restrict__ ws, float* __restrict__ out, int D)
{
    float acc = (threadIdx.x < NBLOCKS) ? ws[threadIdx.x] : 0.0f;

    for (int off = 32; off > 0; off >>= 1)
        acc += __shfl_down(acc, off, 64);

    __shared__ float warp_sums[FINAL_THREADS / 64];
    int lane = threadIdx.x & 63;
    int wid  = threadIdx.x >> 6;
    if (lane == 0) warp_sums[wid] = acc;
    __syncthreads();

    if (threadIdx.x == 0) {
        float s = 0.0f;
        #pragma unroll
        for (int i = 0; i < FINAL_THREADS / 64; ++i) s += warp_sums[i];
        out[0] = s + (float)D;   // plain store — overwrites the 0xAA poison
    }
}

extern "C" void kernel_launch(void* const* d_in, const int* in_sizes, int n_in,
                              void* d_out, int out_size, void* d_ws, size_t ws_size,
                              hipStream_t stream) {
    const float* d = (const float*)d_in[0];
    const float* y = (const float*)d_in[1];
    float* out = (float*)d_out;
    float* ws  = (float*)d_ws;   // NBLOCKS floats of scratch

    int N = in_sizes[0];
    int D = N - 2;

    casamento_partial<<<NBLOCKS, 256, 0, stream>>>(d, y, ws, D);
    casamento_final<<<1, FINAL_THREADS, 0, stream>>>(ws, out, D);
}